// Round 7
// baseline (247.371 us; speedup 1.0000x reference)
//
#include <hip/hip_runtime.h>

typedef __attribute__((ext_vector_type(8))) short bf16x8;
typedef __attribute__((ext_vector_type(4))) float f32x4;
typedef __attribute__((ext_vector_type(8))) unsigned short ushort8;
typedef __attribute__((ext_vector_type(4))) unsigned short ushort4v;

__device__ __forceinline__ unsigned short f2bf(float f) {
  unsigned int u = __float_as_uint(f);
  u = u + 0x7FFFu + ((u >> 16) & 1u);
  return (unsigned short)(u >> 16);
}
__device__ __forceinline__ float bflo(unsigned int u) { return __uint_as_float(u << 16); }
__device__ __forceinline__ float bfhi(unsigned int u) { return __uint_as_float(u & 0xFFFF0000u); }

#define GLOAD_LDS16(g, l)                                                            \
  __builtin_amdgcn_global_load_lds((const __attribute__((address_space(1))) void*)(g), \
                                   (__attribute__((address_space(3))) void*)(l), 16, 0, 0)

// ---------------- fused: weight-image prep (blocks 0..7) ∥ degree+rank (blocks 8+) ----------
__global__ void k_prep_degrank(const float* __restrict__ W, const float* __restrict__ Wr,
                               unsigned short* __restrict__ Wb,
                               const int* __restrict__ dst, int* __restrict__ deg,
                               int* __restrict__ rank, int E) {
  if (blockIdx.x < 8) {
    int t = blockIdx.x * 256 + threadIdx.x;  // 0..2047
    int col = t >> 3, g = t & 7;
    const float* Ws = (col < 128) ? (W + col) : (Wr + (col - 128));
#pragma unroll
    for (int kt = 0; kt < 4; ++kt) {
      ushort8 u;
#pragma unroll
      for (int j = 0; j < 8; ++j) u[j] = f2bf(Ws[(size_t)(kt * 64 + g * 8 + j) * 128]);
      *(ushort8*)&Wb[kt * 16384 + col * 64 + ((g ^ (col & 7)) * 8)] = u;
    }
    return;
  }
  int base = ((blockIdx.x - 8) * 256 + threadIdx.x) * 4;
  if (base + 3 < E) {
    int4 d = *(const int4*)(dst + base);
    int r0 = atomicAdd(&deg[d.x], 1);
    int r1 = atomicAdd(&deg[d.y], 1);
    int r2 = atomicAdd(&deg[d.z], 1);
    int r3 = atomicAdd(&deg[d.w], 1);
    *(int4*)(rank + base) = make_int4(r0, r1, r2, r3);
  } else {
    for (int e = base; e < E; ++e) rank[e] = atomicAdd(&deg[dst[e]], 1);
  }
}

// ---------------- 3-kernel exclusive scan over deg (1024 elems/block) ----------------
__global__ void k_scanA(const int* __restrict__ deg, int* __restrict__ bsums, int N) {
  __shared__ int s[256];
  int t = threadIdx.x;
  int base = blockIdx.x * 1024 + t * 4;
  int ts = 0;
#pragma unroll
  for (int j = 0; j < 4; ++j) { int idx = base + j; ts += (idx < N) ? deg[idx] : 0; }
  s[t] = ts; __syncthreads();
  for (int off = 1; off < 256; off <<= 1) {
    int v = (t >= off) ? s[t - off] : 0;
    __syncthreads();
    s[t] += v;
    __syncthreads();
  }
  if (t == 255) bsums[blockIdx.x] = s[255];
}

__global__ void k_scanB(int* bsums, int nb) {
  __shared__ int s[128];
  int t = threadIdx.x;
  int v = (t < nb) ? bsums[t] : 0;
  s[t] = v; __syncthreads();
  for (int off = 1; off < 128; off <<= 1) {
    int a = (t >= off) ? s[t - off] : 0;
    __syncthreads();
    s[t] += a;
    __syncthreads();
  }
  if (t < nb) bsums[t] = s[t] - v;  // exclusive
}

// scanC + fused dinv = rsqrt(deg+1)
__global__ void k_scanC_dinv(const int* __restrict__ deg, const int* __restrict__ bsums,
                             int* __restrict__ start, float* __restrict__ dinv, int N) {
  __shared__ int s[256];
  int t = threadIdx.x;
  int base = blockIdx.x * 1024 + t * 4;
  int v[4]; int ts = 0;
#pragma unroll
  for (int j = 0; j < 4; ++j) { int idx = base + j; v[j] = (idx < N) ? deg[idx] : 0; ts += v[j]; }
  s[t] = ts; __syncthreads();
  for (int off = 1; off < 256; off <<= 1) {
    int a = (t >= off) ? s[t - off] : 0;
    __syncthreads();
    s[t] += a;
    __syncthreads();
  }
  int run = bsums[blockIdx.x] + s[t] - ts;
#pragma unroll
  for (int j = 0; j < 4; ++j) {
    int idx = base + j;
    if (idx < N) {
      start[idx] = run;
      dinv[idx] = rsqrtf((float)(v[j] + 1));
    }
    run += v[j];
  }
}

// ---------------- fused: dual GEMM (even blocks) ∥ CSR slot fill (odd blocks) ----------------
// gemm: BM=128 rows/block, 8 waves. hs = bf16((x@W)*dinv) ; res = x@Wr + br.
// fill: atomic-free scatter ssrc[start[dst]+rank] = src, 4 edges/thread.
// LDS 50 KB -> 3 blocks/CU; even/odd interleave keeps ~1.5 of each role per CU.
__global__ __launch_bounds__(512) void k_gemm_fill(
    const float* __restrict__ x, const unsigned short* __restrict__ Wb,
    const float* __restrict__ br, const float* __restrict__ dinv,
    unsigned short* __restrict__ hs, float* res, int N,
    const int* __restrict__ src, const int* __restrict__ dst,
    const int* __restrict__ start, const int* __restrict__ rank,
    int* __restrict__ ssrc, int E)
{
  __shared__ unsigned short xt[128][72];
  __shared__ unsigned short wt[256 * 64];
  int tid = threadIdx.x;

  if (blockIdx.x & 1) {
    // ---- fill role ----
    int base = ((blockIdx.x >> 1) * 512 + tid) * 4;
    if (base + 3 < E) {
      int4 d = *(const int4*)(dst + base);
      int4 r = *(const int4*)(rank + base);
      int4 s = *(const int4*)(src + base);
      ssrc[start[d.x] + r.x] = s.x;
      ssrc[start[d.y] + r.y] = s.y;
      ssrc[start[d.z] + r.z] = s.z;
      ssrc[start[d.w] + r.w] = s.w;
    } else {
      for (int e = base; e < E; ++e) ssrc[start[dst[e]] + rank[e]] = src[e];
    }
    return;
  }

  // ---- gemm role ----
  int lane = tid & 63, w = tid >> 6;
  int lo = lane & 15, hi = lane >> 4;
  int brow = (blockIdx.x >> 1) * 128;

  f32x4 acc[16];
#pragma unroll
  for (int c = 0; c < 16; ++c) acc[c] = (f32x4){0.f, 0.f, 0.f, 0.f};

  for (int kt = 0; kt < 4; ++kt) {
    int k0 = kt * 64;
    const unsigned short* gw = Wb + kt * 16384;
#pragma unroll
    for (int i = 0; i < 4; ++i) {
      int off = i * 4096 + tid * 8;  // ushort offset; lane-linear 16B
      GLOAD_LDS16(gw + off, &wt[off]);
    }
#pragma unroll
    for (int r = 0; r < 4; ++r) {
      int idx = tid + 512 * r;          // 0..2047
      int row = idx >> 4, kq = idx & 15;
      int node = brow + row;
      float4 v = make_float4(0.f, 0.f, 0.f, 0.f);
      if (node < N) v = *(const float4*)(x + (size_t)node * 256 + k0 + kq * 4);
      ushort4v u;
      u[0] = f2bf(v.x); u[1] = f2bf(v.y); u[2] = f2bf(v.z); u[3] = f2bf(v.w);
      *(ushort4v*)(&xt[row][kq * 4]) = u;
    }
    __syncthreads();
#pragma unroll
    for (int kk = 0; kk < 2; ++kk) {
      bf16x8 a = *(const bf16x8*)(&xt[w * 16 + lo][kk * 32 + hi * 8]);
      int gsw = ((kk * 4 + hi) ^ (lo & 7)) * 8;
#pragma unroll
      for (int c = 0; c < 16; ++c) {
        bf16x8 b = *(const bf16x8*)(&wt[(c * 16 + lo) * 64 + gsw]);
        acc[c] = __builtin_amdgcn_mfma_f32_16x16x32_bf16(a, b, acc[c], 0, 0, 0);
      }
    }
    __syncthreads();
  }
  // epilogue: D row = hi*4+reg, col = lo
#pragma unroll
  for (int c = 0; c < 16; ++c) {
    int colo = c * 16 + lo;
#pragma unroll
    for (int rg = 0; rg < 4; ++rg) {
      int row = brow + w * 16 + hi * 4 + rg;
      if (row < N) {
        float v = acc[c][rg];
        if (colo < 128) hs[(size_t)row * 128 + colo] = f2bf(v * dinv[row]);
        else            res[(size_t)row * 128 + (colo - 128)] = v + br[colo - 128];
      }
    }
  }
}

// ---------------- per-node aggregation + bias + residual + LayerNorm + ReLU ----------------
__global__ __launch_bounds__(256) void k_agg(
    const unsigned int* __restrict__ hsb, const float* resin,
    const float* __restrict__ dinv, const int* __restrict__ start,
    const int* __restrict__ deg, const int* __restrict__ ssrc,
    const float* __restrict__ bias, const float* __restrict__ gamma,
    const float* __restrict__ beta, float* out, int N)
{
  int node = blockIdx.x * 4 + (threadIdx.x >> 6);
  int lane = threadIdx.x & 63;
  if (node >= N) return;
  unsigned int su = hsb[(size_t)node * 64 + lane];  // self-loop (hs already * dinv[src])
  float ax = bflo(su), ay = bfhi(su);
  int s0 = start[node], cnt = deg[node];
  const int* sp = ssrc + s0;
  int e = 0;
  for (; e + 8 <= cnt; e += 8) {
    int i0 = sp[e + 0], i1 = sp[e + 1], i2 = sp[e + 2], i3 = sp[e + 3];
    int i4 = sp[e + 4], i5 = sp[e + 5], i6 = sp[e + 6], i7 = sp[e + 7];
    unsigned int u0 = hsb[(size_t)i0 * 64 + lane];
    unsigned int u1 = hsb[(size_t)i1 * 64 + lane];
    unsigned int u2 = hsb[(size_t)i2 * 64 + lane];
    unsigned int u3 = hsb[(size_t)i3 * 64 + lane];
    unsigned int u4 = hsb[(size_t)i4 * 64 + lane];
    unsigned int u5 = hsb[(size_t)i5 * 64 + lane];
    unsigned int u6 = hsb[(size_t)i6 * 64 + lane];
    unsigned int u7 = hsb[(size_t)i7 * 64 + lane];
    float x01 = bflo(u0) + bflo(u1), x23 = bflo(u2) + bflo(u3);
    float x45 = bflo(u4) + bflo(u5), x67 = bflo(u6) + bflo(u7);
    float y01 = bfhi(u0) + bfhi(u1), y23 = bfhi(u2) + bfhi(u3);
    float y45 = bfhi(u4) + bfhi(u5), y67 = bfhi(u6) + bfhi(u7);
    ax += (x01 + x23) + (x45 + x67);
    ay += (y01 + y23) + (y45 + y67);
  }
  for (; e + 4 <= cnt; e += 4) {
    int i0 = sp[e + 0], i1 = sp[e + 1], i2 = sp[e + 2], i3 = sp[e + 3];
    unsigned int u0 = hsb[(size_t)i0 * 64 + lane];
    unsigned int u1 = hsb[(size_t)i1 * 64 + lane];
    unsigned int u2 = hsb[(size_t)i2 * 64 + lane];
    unsigned int u3 = hsb[(size_t)i3 * 64 + lane];
    ax += (bflo(u0) + bflo(u1)) + (bflo(u2) + bflo(u3));
    ay += (bfhi(u0) + bfhi(u1)) + (bfhi(u2) + bfhi(u3));
  }
  for (; e < cnt; ++e) {
    int s = sp[e];
    unsigned int u = hsb[(size_t)s * 64 + lane];
    ax += bflo(u); ay += bfhi(u);
  }
  float di = dinv[node];
  float2 r  = ((const float2*)resin)[(size_t)node * 64 + lane];
  float2 bb = ((const float2*)bias)[lane];
  float vx = ax * di + bb.x + r.x;
  float vy = ay * di + bb.y + r.y;
  float sum = vx + vy;
#pragma unroll
  for (int off = 32; off >= 1; off >>= 1) sum += __shfl_xor(sum, off, 64);
  float mean = sum * (1.0f / 128.0f);
  float dx = vx - mean, dy = vy - mean;
  float sq = dx * dx + dy * dy;
#pragma unroll
  for (int off = 32; off >= 1; off >>= 1) sq += __shfl_xor(sq, off, 64);
  float rstd = rsqrtf(sq * (1.0f / 128.0f) + 1e-5f);
  float2 g  = ((const float2*)gamma)[lane];
  float2 be = ((const float2*)beta)[lane];
  float ox = fmaxf(dx * rstd * g.x + be.x, 0.0f);
  float oy = fmaxf(dy * rstd * g.y + be.y, 0.0f);
  ((float2*)out)[(size_t)node * 64 + lane] = make_float2(ox, oy);
}

extern "C" void kernel_launch(void* const* d_in, const int* in_sizes, int n_in,
                              void* d_out, int out_size, void* d_ws, size_t ws_size,
                              hipStream_t stream) {
  const float* x     = (const float*)d_in[0];
  const int*   eidx  = (const int*)d_in[1];
  const float* W     = (const float*)d_in[2];
  const float* b     = (const float*)d_in[3];
  const float* Wr    = (const float*)d_in[4];
  const float* br    = (const float*)d_in[5];
  const float* gamma = (const float*)d_in[6];
  const float* beta  = (const float*)d_in[7];
  float* out = (float*)d_out;

  int N = in_sizes[0] / 256;
  int E = in_sizes[1] / 2;
  const int* srcI = eidx;
  const int* dstI = eidx + E;

  char* w = (char*)d_ws;
  size_t off = 0;
  auto alloc = [&](size_t bytes) -> void* {
    void* p = w + off;
    off += (bytes + 255) & ~(size_t)255;
    return p;
  };
  unsigned short* hs   = (unsigned short*)alloc((size_t)N * 128 * 2);
  int*   deg    = (int*)alloc((size_t)N * 4);
  float* dinv   = (float*)alloc((size_t)N * 4);
  int*   start  = (int*)alloc((size_t)N * 4);
  int*   rank   = (int*)alloc((size_t)E * 4);
  int*   ssrc   = (int*)alloc((size_t)E * 4);
  unsigned short* Wb = (unsigned short*)alloc((size_t)4 * 16384 * 2);
  int nb = (N + 1023) / 1024;
  int*   bsums  = (int*)alloc(((size_t)nb + 32) * 4);

  hipMemsetAsync(deg, 0, (size_t)N * 4, stream);
  int dgrid = (E / 4 + 255) / 256;           // 1563 degrank blocks
  k_prep_degrank<<<8 + dgrid, 256, 0, stream>>>(W, Wr, Wb, dstI, deg, rank, E);
  k_scanA<<<nb, 256, 0, stream>>>(deg, bsums, N);
  k_scanB<<<1, 128, 0, stream>>>(bsums, nb);
  k_scanC_dinv<<<nb, 256, 0, stream>>>(deg, bsums, start, dinv, N);
  int ggrid = (N + 127) / 128;               // 782 gemm blocks; fill needs <= 782 too
  k_gemm_fill<<<2 * ggrid, 512, 0, stream>>>(x, Wb, br, dinv, hs, out, N,
                                             srcI, dstI, start, rank, ssrc, E);
  k_agg  <<<(N + 3) / 4, 256, 0, stream>>>((const unsigned int*)hs, out, dinv, start, deg, ssrc,
                                           b, gamma, beta, out, N);
}